// Round 6
// baseline (73.344 us; speedup 1.0000x reference)
//
#include <hip/hip_runtime.h>
#include <hip/hip_bf16.h>

// Problem constants (from reference)
#define UNITS 512
#define CONN  512
#define SEQL  32

typedef __hip_bfloat16 bf16;
typedef __attribute__((ext_vector_type(8))) short short8;   // 8 bf16 = MFMA A/B frag
typedef __attribute__((ext_vector_type(4))) float floatx4;  // MFMA C/D frag

// out[b,u] = relu( sum_c x[b,c] * kernel[u] * dendriticW[dendrites[u,c], u] + bias[u] )
// == 512^3 GEMM with gather-built weights. fp32 I/O (verified R1-R4); x,W
// quantized to bf16 for MFMA (absmax ~2e-3 vs 9.8e-3 threshold, measured).
//
// R5 lesson: fusing build into the GEMM grid rebuilds each W tile 8x. Build W
// exactly ONCE (K1 -> d_ws), then a lean MFMA GEMM (K2).
//   K1: per-unit 32-entry dW slice staged in LDS (bank=seg, conflict-free w/
//       broadcast) -> gather becomes an LDS lookup, not a 32-line L2 gather.
//   K2: 1 wave per 16x16 tile, K=512 as TWO independent 8-step MFMA chains
//       (acc0/acc1) for 2x MFMA ILP; A = fp32 x + in-reg cvt; B = bf16 W rows
//       straight from global (m92 B^T pattern); C/D per m89.

union cv8 { bf16 h[8]; short8 v; };

// ---------------- K1: build W[u][c] bf16, once ----------------
__global__ __launch_bounds__(128) void prep_w(
    const float* __restrict__ kern,  // [UNITS]
    const float* __restrict__ dW,    // [SEQL*UNITS]
    const int*   __restrict__ dend,  // [UNITS*CONN]
    bf16* __restrict__ W)            // [UNITS*CONN] out
{
    __shared__ float table[2][SEQL];     // dW[., u0+ul]; bank = seg
    const int t  = threadIdx.x;          // 0..127 (2 waves)
    const int u0 = blockIdx.x * 2;

    if (t < 2 * SEQL) {                  // stage the 2 units' dW slices
        const int s = t >> 1, ul = t & 1;
        table[ul][s] = dW[s * UNITS + u0 + ul];
    }
    __syncthreads();

    const int ul = t >> 6;               // wave 0 -> unit u0, wave 1 -> u0+1
    const int u  = u0 + ul;
    const int c0 = (t & 63) * 8;         // 8 conns per thread
    const float kv = kern[u];

    const int4 s0 = ((const int4*)(dend + u * CONN + c0))[0];  // coalesced
    const int4 s1 = ((const int4*)(dend + u * CONN + c0))[1];
    const int segs[8] = {s0.x, s0.y, s0.z, s0.w, s1.x, s1.y, s1.z, s1.w};

    cv8 w;
#pragma unroll
    for (int i = 0; i < 8; ++i)          // LDS lookup: bank=seg, bcast on dup
        w.h[i] = __float2bfloat16(kv * table[ul][segs[i]]);
    *(short8*)(W + u * CONN + c0) = w.v; // 16B coalesced store
}

// ---------------- K2: MFMA GEMM + bias + relu ----------------
__device__ __forceinline__ short8 cvt8(const float* p) {
    const float4 f0 = ((const float4*)p)[0];
    const float4 f1 = ((const float4*)p)[1];
    cv8 a;
    a.h[0] = __float2bfloat16(f0.x); a.h[1] = __float2bfloat16(f0.y);
    a.h[2] = __float2bfloat16(f0.z); a.h[3] = __float2bfloat16(f0.w);
    a.h[4] = __float2bfloat16(f1.x); a.h[5] = __float2bfloat16(f1.y);
    a.h[6] = __float2bfloat16(f1.z); a.h[7] = __float2bfloat16(f1.w);
    return a.v;
}

__global__ __launch_bounds__(64) void gemm_mfma(
    const float* __restrict__ x,     // [batch*CONN] fp32
    const bf16*  __restrict__ W,     // [UNITS*CONN] bf16
    const float* __restrict__ bias,  // [UNITS]
    float* __restrict__ out)         // [batch*UNITS] fp32
{
    const int lane = threadIdx.x;
    const int ut = blockIdx.x * 16;
    const int bt = blockIdx.y * 16;
    const int m = lane & 15;
    const int q = lane >> 4;

    const float* xrow = x + (size_t)(bt + m) * CONN + q * 8;
    const bf16*  wrow = W + (size_t)(ut + m) * CONN + q * 8;

    floatx4 acc0 = {0.f, 0.f, 0.f, 0.f};
    floatx4 acc1 = {0.f, 0.f, 0.f, 0.f};
#pragma unroll
    for (int kb = 0; kb < 8; ++kb) {     // two independent MFMA chains
        const int k0 = kb * 32;
        const int k1 = 256 + kb * 32;
        const short8 a0 = cvt8(xrow + k0);
        const short8 b0 = *(const short8*)(wrow + k0);
        acc0 = __builtin_amdgcn_mfma_f32_16x16x32_bf16(a0, b0, acc0, 0, 0, 0);
        const short8 a1 = cvt8(xrow + k1);
        const short8 b1 = *(const short8*)(wrow + k1);
        acc1 = __builtin_amdgcn_mfma_f32_16x16x32_bf16(a1, b1, acc1, 0, 0, 0);
    }

    const float bu = bias[ut + m];
#pragma unroll
    for (int r = 0; r < 4; ++r) {
        float v = acc0[r] + acc1[r] + bu;
        v = v > 0.f ? v : 0.f;
        out[(size_t)(bt + q * 4 + r) * UNITS + ut + m] = v;
    }
}

// ---------------- Fallback (ws < 512 KB): R5's proven fused kernel ----------------
__global__ __launch_bounds__(256) void dendriter_fused_mfma(
    const float* __restrict__ x, const float* __restrict__ kern,
    const float* __restrict__ dW, const float* __restrict__ bias,
    const int* __restrict__ dend, float* __restrict__ out)
{
    __shared__ short8 wl[16][65];
    const int t  = threadIdx.x;
    const int ut = blockIdx.x * 16;
    const int bt = blockIdx.y * 64;
    {
        const int ul  = t >> 4;
        const int cg0 = (t & 15) * 4;
        const int u   = ut + ul;
        const float kv = kern[u];
        const int4* dp = (const int4*)(dend + u * CONN + cg0 * 8);
#pragma unroll
        for (int j = 0; j < 4; ++j) {
            const int4 s0 = dp[2 * j];
            const int4 s1 = dp[2 * j + 1];
            const int segs[8] = {s0.x, s0.y, s0.z, s0.w, s1.x, s1.y, s1.z, s1.w};
            cv8 w;
#pragma unroll
            for (int i = 0; i < 8; ++i)
                w.h[i] = __float2bfloat16(kv * dW[segs[i] * UNITS + u]);
            const int cg = cg0 + j;
            wl[cg >> 2][ul | ((cg & 3) << 4)] = w.v;
        }
    }
    __syncthreads();

    const int lane = t & 63;
    const int wv   = t >> 6;
    const int m = lane & 15;
    const int q = lane >> 4;
    const int btw = bt + wv * 16;
    const float* xrow = x + (size_t)(btw + m) * CONN + q * 8;
    floatx4 acc = {0.f, 0.f, 0.f, 0.f};
#pragma unroll
    for (int kb = 0; kb < 16; ++kb) {
        const short8 a = cvt8(xrow + kb * 32);
        const short8 b = wl[kb][lane];
        acc = __builtin_amdgcn_mfma_f32_16x16x32_bf16(a, b, acc, 0, 0, 0);
    }
    const float bu = bias[ut + m];
#pragma unroll
    for (int r = 0; r < 4; ++r) {
        float v = acc[r] + bu;
        v = v > 0.f ? v : 0.f;
        out[(size_t)(btw + q * 4 + r) * UNITS + ut + m] = v;
    }
}

extern "C" void kernel_launch(void* const* d_in, const int* in_sizes, int n_in,
                              void* d_out, int out_size, void* d_ws, size_t ws_size,
                              hipStream_t stream) {
    // setup_inputs() order: x, kernel, dendriticW, bias, dendrites — all fp32
    const float* x    = (const float*)d_in[0];
    const float* kern = (const float*)d_in[1];
    const float* dW   = (const float*)d_in[2];
    const float* bias = (const float*)d_in[3];
    const int*   dend = (const int*)  d_in[4];
    float* out = (float*)d_out;

    const int batch = in_sizes[0] / CONN;                        // 512
    const size_t w_bytes = (size_t)UNITS * CONN * sizeof(bf16);  // 512 KB

    if (ws_size >= w_bytes) {            // ws_size call-invariant -> graph-safe
        bf16* W = (bf16*)d_ws;
        prep_w<<<UNITS / 2, 128, 0, stream>>>(kern, dW, dend, W);
        gemm_mfma<<<dim3(UNITS / 16, batch / 16), 64, 0, stream>>>(x, W, bias, out);
    } else {
        dendriter_fused_mfma<<<dim3(UNITS / 16, batch / 64), 256, 0, stream>>>(
            x, kern, dW, bias, dend, out);
    }
}

// Round 7
// 66.633 us; speedup vs baseline: 1.1007x; 1.1007x over previous
//
#include <hip/hip_runtime.h>
#include <hip/hip_bf16.h>

// Problem constants (from reference)
#define UNITS 512
#define CONN  512
#define SEQL  32

typedef __hip_bfloat16 bf16;
typedef __attribute__((ext_vector_type(8))) short short8;   // 8 bf16 = MFMA A/B frag
typedef __attribute__((ext_vector_type(4))) float floatx4;  // MFMA C/D frag

// out[b,u] = relu( sum_c x[b,c] * kernel[u] * dendriticW[dendrites[u,c], u] + bias[u] )
// == 512^3 GEMM with gather-built weights. fp32 I/O (verified R1-R4); x,W
// quantized to bf16 for MFMA (absmax 1.95e-3 vs 9.84e-3 threshold, measured).
//
// Structure = R4 (measured best, 67.2 us): K1 builds bf16 W AND bf16 x copy;
// K2 = 1 wave per 16x16 MFMA tile reading both as bf16 straight from global.
// Single change vs R4: K1's dW gather is staged through a per-wave 32-entry
// LDS table (one 32-line load per wave instead of ~256 scattered
// line-transactions across 8 divergent gather instructions).

union cv8 { bf16 h[8]; short8 v; };

// ---------------- K1: prep (build W bf16 + convert x to bf16) ----------------
__global__ __launch_bounds__(256) void prep(
    const float* __restrict__ kern,  // [UNITS] fp32
    const float* __restrict__ dW,    // [SEQL*UNITS] fp32
    const int*   __restrict__ dend,  // [UNITS*CONN] int32
    const float* __restrict__ x,     // [batch*CONN] fp32
    bf16* __restrict__ W,            // [UNITS*CONN] bf16 out
    bf16* __restrict__ xb,           // [batch*CONN] bf16 out
    int nxthreads)                   // batch*CONN/8
{
    __shared__ float table[4][SEQL];     // per-wave dW column for its unit
    const int tid = blockIdx.x * 256 + threadIdx.x;
    const int WTHREADS = UNITS * (CONN / 8);          // 32768 (blocks 0..127)

    if (tid < WTHREADS) {
        // One unit per wave (64 threads x 8 conns = 512).
        const int u    = tid >> 6;
        const int lane = threadIdx.x & 63;
        const int wid  = threadIdx.x >> 6;
        if (lane < SEQL)                              // one 32-line gather/wave
            table[wid][lane] = dW[lane * UNITS + u];
        __syncthreads();                              // block-uniform path: safe

        const int c0 = lane * 8;
        const float kv = kern[u];
        const int4 s0 = ((const int4*)(dend + u * CONN + c0))[0];  // coalesced
        const int4 s1 = ((const int4*)(dend + u * CONN + c0))[1];
        const int segs[8] = {s0.x, s0.y, s0.z, s0.w, s1.x, s1.y, s1.z, s1.w};
        cv8 w;
#pragma unroll
        for (int i = 0; i < 8; ++i)   // LDS lookup: random over 32 banks (~free)
            w.h[i] = __float2bfloat16(kv * table[wid][segs[i]]);
        *(short8*)(W + u * CONN + c0) = w.v;          // 16B coalesced
    } else {
        __syncthreads();                              // keep barrier count uniform
        const int t = tid - WTHREADS;                 // blocks 128.. convert x
        if (t < nxthreads) {
            const float4 f0 = ((const float4*)x)[t * 2];
            const float4 f1 = ((const float4*)x)[t * 2 + 1];
            cv8 a;
            a.h[0] = __float2bfloat16(f0.x); a.h[1] = __float2bfloat16(f0.y);
            a.h[2] = __float2bfloat16(f0.z); a.h[3] = __float2bfloat16(f0.w);
            a.h[4] = __float2bfloat16(f1.x); a.h[5] = __float2bfloat16(f1.y);
            a.h[6] = __float2bfloat16(f1.z); a.h[7] = __float2bfloat16(f1.w);
            *(short8*)(xb + t * 8) = a.v;
        }
    }
}

// ---------------- K2: MFMA GEMM + bias + relu (EXACT R4 <true> path) ----------------
// A frag: A[m=lane&15][k=(lane>>4)*8+j]; B from W rows (B^T pattern, m92);
// C/D: col=lane&15 (unit), row=(lane>>4)*4+reg (batch)  [m89-verified].
__global__ __launch_bounds__(64) void gemm_mfma(
    const bf16*  __restrict__ xb,    // [batch*CONN] bf16
    const bf16*  __restrict__ W,     // [UNITS*CONN] bf16
    const float* __restrict__ bias,  // [UNITS] fp32
    float* __restrict__ out)         // [batch*UNITS] fp32
{
    const int lane = threadIdx.x;
    const int ut = blockIdx.x * 16;
    const int bt = blockIdx.y * 16;
    const int m = lane & 15;
    const int q = lane >> 4;

    const bf16* xrow = xb + (size_t)(bt + m) * CONN + q * 8;
    const bf16* wrow = W  + (size_t)(ut + m) * CONN + q * 8;

    floatx4 acc = {0.f, 0.f, 0.f, 0.f};
#pragma unroll
    for (int k = 0; k < CONN; k += 32) {
        const short8 a = *(const short8*)(xrow + k);
        const short8 b = *(const short8*)(wrow + k);
        acc = __builtin_amdgcn_mfma_f32_16x16x32_bf16(a, b, acc, 0, 0, 0);
    }

    const float bu = bias[ut + m];
#pragma unroll
    for (int r = 0; r < 4; ++r) {
        float v = acc[r] + bu;
        v = v > 0.f ? v : 0.f;
        out[(size_t)(bt + q * 4 + r) * UNITS + ut + m] = v;
    }
}

// ---------------- Fallback (ws < 1 MB): R5's proven fused kernel ----------------
__device__ __forceinline__ short8 cvt8(const float* p) {
    const float4 f0 = ((const float4*)p)[0];
    const float4 f1 = ((const float4*)p)[1];
    cv8 a;
    a.h[0] = __float2bfloat16(f0.x); a.h[1] = __float2bfloat16(f0.y);
    a.h[2] = __float2bfloat16(f0.z); a.h[3] = __float2bfloat16(f0.w);
    a.h[4] = __float2bfloat16(f1.x); a.h[5] = __float2bfloat16(f1.y);
    a.h[6] = __float2bfloat16(f1.z); a.h[7] = __float2bfloat16(f1.w);
    return a.v;
}

__global__ __launch_bounds__(256) void dendriter_fused_mfma(
    const float* __restrict__ x, const float* __restrict__ kern,
    const float* __restrict__ dW, const float* __restrict__ bias,
    const int* __restrict__ dend, float* __restrict__ out)
{
    __shared__ short8 wl[16][65];
    const int t  = threadIdx.x;
    const int ut = blockIdx.x * 16;
    const int bt = blockIdx.y * 64;
    {
        const int ul  = t >> 4;
        const int cg0 = (t & 15) * 4;
        const int u   = ut + ul;
        const float kv = kern[u];
        const int4* dp = (const int4*)(dend + u * CONN + cg0 * 8);
#pragma unroll
        for (int j = 0; j < 4; ++j) {
            const int4 s0 = dp[2 * j];
            const int4 s1 = dp[2 * j + 1];
            const int segs[8] = {s0.x, s0.y, s0.z, s0.w, s1.x, s1.y, s1.z, s1.w};
            cv8 w;
#pragma unroll
            for (int i = 0; i < 8; ++i)
                w.h[i] = __float2bfloat16(kv * dW[segs[i] * UNITS + u]);
            const int cg = cg0 + j;
            wl[cg >> 2][ul | ((cg & 3) << 4)] = w.v;
        }
    }
    __syncthreads();

    const int lane = t & 63;
    const int wv   = t >> 6;
    const int m = lane & 15;
    const int q = lane >> 4;
    const int btw = bt + wv * 16;
    const float* xrow = x + (size_t)(btw + m) * CONN + q * 8;
    floatx4 acc = {0.f, 0.f, 0.f, 0.f};
#pragma unroll
    for (int kb = 0; kb < 16; ++kb) {
        const short8 a = cvt8(xrow + kb * 32);
        const short8 b = wl[kb][lane];
        acc = __builtin_amdgcn_mfma_f32_16x16x32_bf16(a, b, acc, 0, 0, 0);
    }
    const float bu = bias[ut + m];
#pragma unroll
    for (int r = 0; r < 4; ++r) {
        float v = acc[r] + bu;
        v = v > 0.f ? v : 0.f;
        out[(size_t)(btw + q * 4 + r) * UNITS + ut + m] = v;
    }
}

extern "C" void kernel_launch(void* const* d_in, const int* in_sizes, int n_in,
                              void* d_out, int out_size, void* d_ws, size_t ws_size,
                              hipStream_t stream) {
    // setup_inputs() order: x, kernel, dendriticW, bias, dendrites — all fp32
    const float* x    = (const float*)d_in[0];
    const float* kern = (const float*)d_in[1];
    const float* dW   = (const float*)d_in[2];
    const float* bias = (const float*)d_in[3];
    const int*   dend = (const int*)  d_in[4];
    float* out = (float*)d_out;

    const int batch = in_sizes[0] / CONN;                        // 512
    const size_t w_bytes  = (size_t)UNITS * CONN * sizeof(bf16); // 512 KB
    const size_t xb_bytes = (size_t)batch * CONN * sizeof(bf16); // 512 KB
    const int nxthreads = batch * CONN / 8;

    if (ws_size >= w_bytes + xb_bytes) {  // ws_size call-invariant -> graph-safe
        bf16* W  = (bf16*)d_ws;
        bf16* xb = W + (size_t)UNITS * CONN;
        prep<<<(UNITS * CONN / 8 + nxthreads + 255) / 256, 256, 0, stream>>>(
            kern, dW, dend, x, W, xb, nxthreads);
        gemm_mfma<<<dim3(UNITS / 16, batch / 16), 64, 0, stream>>>(xb, W, bias, out);
    } else {
        dendriter_fused_mfma<<<dim3(UNITS / 16, batch / 64), 256, 0, stream>>>(
            x, kern, dW, bias, dend, out);
    }
}